// Round 7
// baseline (590.669 us; speedup 1.0000x reference)
//
#include <hip/hip_runtime.h>

typedef unsigned int u32;
typedef unsigned short u16;
typedef __attribute__((ext_vector_type(8))) short short8;
typedef __attribute__((ext_vector_type(16))) float f32x16;

// Problem constants
#define NA   50000      // atoms
#define MN   12         // neighbors
#define FD   128        // atom feature len
#define KD   64         // nbr feature len
#define NMR  600000     // NA*MN edge rows
#define KIN  320        // 2F+K
#define NT2  9375       // NMR/64 tiles (pass A)
#define NBLK2 1024      // pass-A persistent blocks (4/CU at 32 KB LDS)
#define NBLKB 12500     // pass-B blocks: 4 atoms = 48 edge rows each
#define NCH1 1563       // k1 row-chunks of 32 (ceil(50000/32))
#define BN_EPS 1e-5f
#define LOG2E 1.4426950408889634f
#define LN2   0.6931471805599453f

// ---- fast transcendentals: raw v_exp_f32 / v_log_f32 / v_rcp_f32 ----
#if __has_builtin(__builtin_amdgcn_exp2f)
#define EXP2F(x) __builtin_amdgcn_exp2f(x)
#else
#define EXP2F(x) exp2f(x)
#endif
#if __has_builtin(__builtin_amdgcn_logf)
#define LOG2F(x) __builtin_amdgcn_logf(x)
#else
#define LOG2F(x) log2f(x)
#endif
#if __has_builtin(__builtin_amdgcn_rcpf)
#define RCPF(x) __builtin_amdgcn_rcpf(x)
#else
#define RCPF(x) (1.f / (x))
#endif

__device__ __forceinline__ float fast_sigmoid(float x) {
    return RCPF(1.f + EXP2F(-x * LOG2E));    // 1/(1+e^-x)
}
__device__ __forceinline__ float fast_softplus(float x) {
    float e = EXP2F(-fabsf(x) * LOG2E);      // e^{-|x|}
    return fmaxf(x, 0.f) + LN2 * LOG2F(1.f + e);
}

// ---- manual bf16 (RNE) helpers ----
__device__ __forceinline__ u32 f2bf_bits(float f) {
    u32 u = __float_as_uint(f);
    return u + 0x7fffu + ((u >> 16) & 1u);
}
__device__ __forceinline__ u32 pack2(float lo, float hi) {
    return (f2bf_bits(lo) >> 16) | (f2bf_bits(hi) & 0xffff0000u);
}
__device__ __forceinline__ float bflo(u32 u) { return __uint_as_float(u << 16); }
__device__ __forceinline__ float bfhi(u32 u) { return __uint_as_float(u & 0xffff0000u); }
__device__ __forceinline__ short8 pack8(float4 x, float4 y) {
    union { short8 s; uint4 u; } cv;
    cv.u = make_uint4(pack2(x.x, x.y), pack2(x.z, x.w),
                      pack2(y.x, y.y), pack2(y.z, y.w));
    return cv.s;
}

// ---------------------------------------------------------------------------
// K1 (MFMA, persistent): UNCHANGED from round 5 (control).
// ---------------------------------------------------------------------------
__global__ __launch_bounds__(256) void k1_p12(const float* __restrict__ atom,
                                              const float* __restrict__ W,
                                              u16* __restrict__ P12) {
    __shared__ u16 C16[32 * 256];   // 16 KB: one 32-row x 256-col bf16 chunk
    const int t  = threadIdx.x;
    const int w  = t >> 6;
    const int L  = t & 63;
    const int lr = L & 31, lk = L >> 5;
    const int yb = blockIdx.y;      // 0: P1 (k 0..127), 1: P2 (k 128..255)
    const int kw = yb * 128;

    short8 bfrag[2][8];
#pragma unroll
    for (int ct = 0; ct < 2; ct++) {
        const float* wr = &W[(size_t)(w * 64 + ct * 32 + lr) * KIN + kw];
#pragma unroll
        for (int s = 0; s < 8; s++) {
            float4 x = *(const float4*)&wr[s * 16 + lk * 8];
            float4 y = *(const float4*)&wr[s * 16 + lk * 8 + 4];
            bfrag[ct][s] = pack8(x, y);
        }
    }

    int ci = blockIdx.x;
    float4 ax[8], ay[8];
    {
        int row = ci * 32 + lr; if (row > NA - 1) row = NA - 1;
        const float* ar = &atom[(size_t)row * FD];
#pragma unroll
        for (int s = 0; s < 8; s++) {
            ax[s] = *(const float4*)&ar[s * 16 + lk * 8];
            ay[s] = *(const float4*)&ar[s * 16 + lk * 8 + 4];
        }
    }

    for (; ci < NCH1; ci += 256) {
        short8 af[8];
#pragma unroll
        for (int s = 0; s < 8; s++) af[s] = pack8(ax[s], ay[s]);

        const int next = ci + 256;
        if (next < NCH1) {
            int row = next * 32 + lr; if (row > NA - 1) row = NA - 1;
            const float* ar = &atom[(size_t)row * FD];
#pragma unroll
            for (int s = 0; s < 8; s++) {
                ax[s] = *(const float4*)&ar[s * 16 + lk * 8];
                ay[s] = *(const float4*)&ar[s * 16 + lk * 8 + 4];
            }
        }

        f32x16 acc[2];
#pragma unroll
        for (int p = 0; p < 16; p++) { acc[0][p] = 0.f; acc[1][p] = 0.f; }
#pragma unroll
        for (int s = 0; s < 8; s++) {
            acc[0] = __builtin_amdgcn_mfma_f32_32x32x16_bf16(af[s], bfrag[0][s], acc[0], 0, 0, 0);
            acc[1] = __builtin_amdgcn_mfma_f32_32x32x16_bf16(af[s], bfrag[1][s], acc[1], 0, 0, 0);
        }

        __syncthreads();
#pragma unroll
        for (int ct = 0; ct < 2; ct++) {
            const int col = w * 64 + ct * 32 + lr;
#pragma unroll
            for (int p = 0; p < 16; p++) {
                const int r = (p & 3) + 8 * (p >> 2) + 4 * lk;
                C16[r * 256 + col] = (u16)(f2bf_bits(acc[ct][p]) >> 16);
            }
        }
        __syncthreads();

        const int r0 = ci * 32;
#pragma unroll
        for (int i = 0; i < 4; i++) {
            const int flat = t + i * 256;
            const int row  = flat >> 5;
            const int seg  = flat & 31;
            if (r0 + row < NA)
                *(uint4*)&P12[(size_t)(r0 + row) * 512 + yb * 256 + seg * 8] =
                    *(const uint4*)&C16[row * 256 + seg * 8];
        }
    }
}

// ---------------------------------------------------------------------------
// K2 (pass A, BN1 stats): UNCHANGED from round 5 (control).
// ---------------------------------------------------------------------------
__global__ __launch_bounds__(256, 2) void k2_stats(const float* __restrict__ nbr,
                                                   const int* __restrict__ nidx,
                                                   const float* __restrict__ W,
                                                   const u16* __restrict__ P12,
                                                   float* __restrict__ partial1) {
    __shared__ u16 C16[64 * 256];     // 32 KB bf16 staging
    const int t  = threadIdx.x;
    const int w  = t >> 6;
    const int L  = t & 63;
    const int rg = w & 1;
    const int cg = w >> 1;
    const int lr = L & 31;
    const int lk = L >> 5;

    short8 bfrag[4][4];
#pragma unroll
    for (int ct = 0; ct < 4; ct++) {
        const float* wr = &W[(size_t)(cg * 128 + ct * 32 + lr) * KIN + 256];
#pragma unroll
        for (int s = 0; s < 4; s++) {
            float4 x = *(const float4*)&wr[s * 16 + lk * 8];
            float4 y = *(const float4*)&wr[s * 16 + lk * 8 + 4];
            bfrag[ct][s] = pack8(x, y);
        }
    }

    const int c0 = (t & 63) * 4;
    float ssum[4] = {0.f, 0.f, 0.f, 0.f};
    float ssq[4]  = {0.f, 0.f, 0.f, 0.f};

    int tile = blockIdx.x;
    float4 a0[4], a1[4];
    {
        const float* ar = &nbr[(size_t)(tile * 64 + rg * 32 + lr) * KD];
#pragma unroll
        for (int s = 0; s < 4; s++) {
            a0[s] = *(const float4*)&ar[s * 16 + lk * 8];
            a1[s] = *(const float4*)&ar[s * 16 + lk * 8 + 4];
        }
    }

    for (; tile < NT2; tile += NBLK2) {
        short8 af[4];
#pragma unroll
        for (int s = 0; s < 4; s++) af[s] = pack8(a0[s], a1[s]);

        const int next = tile + NBLK2;
        if (next < NT2) {
            const float* ar = &nbr[(size_t)(next * 64 + rg * 32 + lr) * KD];
#pragma unroll
            for (int s = 0; s < 4; s++) {
                a0[s] = *(const float4*)&ar[s * 16 + lk * 8];
                a1[s] = *(const float4*)&ar[s * 16 + lk * 8 + 4];
            }
        }

        f32x16 acc[4];
#pragma unroll
        for (int ct = 0; ct < 4; ct++)
#pragma unroll
            for (int p = 0; p < 16; p++) acc[ct][p] = 0.f;
#pragma unroll
        for (int s = 0; s < 4; s++)
#pragma unroll
            for (int ct = 0; ct < 4; ct++)
                acc[ct] = __builtin_amdgcn_mfma_f32_32x32x16_bf16(
                              af[s], bfrag[ct][s], acc[ct], 0, 0, 0);

        __syncthreads();
#pragma unroll
        for (int ct = 0; ct < 4; ct++) {
            const int col = cg * 128 + ct * 32 + lr;
#pragma unroll
            for (int p = 0; p < 16; p++) {
                int r = rg * 32 + (p & 3) + 8 * (p >> 2) + 4 * lk;
                C16[r * 256 + col] = (u16)(f2bf_bits(acc[ct][p]) >> 16);
            }
        }
        __syncthreads();

#pragma unroll 8
        for (int rr = 0; rr < 16; rr++) {
            const int lrow = rr * 4 + w;
            const int g    = tile * 64 + lrow;
            const u32 n    = (u32)g / 12u;
            const int iv   = nidx[g];
            const float mk = (iv != 0) ? 1.f : 0.f;
            uint2 qv = *(const uint2*)&C16[lrow * 256 + c0];
            uint2 u1 = *(const uint2*)&P12[(size_t)n * 512 + c0];
            uint2 u2 = *(const uint2*)&P12[(size_t)iv * 512 + 256 + c0];
            float v0 = bflo(u1.x) + mk * (bflo(u2.x) + bflo(qv.x));
            float v1 = bfhi(u1.x) + mk * (bfhi(u2.x) + bfhi(qv.x));
            float v2 = bflo(u1.y) + mk * (bflo(u2.y) + bflo(qv.y));
            float v3 = bfhi(u1.y) + mk * (bfhi(u2.y) + bfhi(qv.y));
            ssum[0] += v0; ssq[0] = fmaf(v0, v0, ssq[0]);
            ssum[1] += v1; ssq[1] = fmaf(v1, v1, ssq[1]);
            ssum[2] += v2; ssq[2] = fmaf(v2, v2, ssq[2]);
            ssum[3] += v3; ssq[3] = fmaf(v3, v3, ssq[3]);
        }
    }

    __syncthreads();
    float* red = (float*)C16;
#pragma unroll
    for (int qq = 0; qq < 4; qq++) red[w * 256 + c0 + qq] = ssum[qq];
    __syncthreads();
    {
        float s = red[t] + red[256 + t] + red[512 + t] + red[768 + t];
        partial1[(size_t)blockIdx.x * 512 + t] = s;
    }
    __syncthreads();
#pragma unroll
    for (int qq = 0; qq < 4; qq++) red[w * 256 + c0 + qq] = ssq[qq];
    __syncthreads();
    {
        float s = red[t] + red[256 + t] + red[512 + t] + red[768 + t];
        partial1[(size_t)blockIdx.x * 512 + 256 + t] = s;
    }
}

// ---------------------------------------------------------------------------
// K2b: finalize BN1 (unchanged)
// ---------------------------------------------------------------------------
__global__ __launch_bounds__(256) void k2b_bn1(const float* __restrict__ partial1,
                                               const float* __restrict__ gamma1,
                                               const float* __restrict__ beta1,
                                               float* __restrict__ bn1) {
    __shared__ double sh[8];
    const int c = blockIdx.x;
    const int t = threadIdx.x;
    double s = 0.0, q = 0.0;
    for (int b = t; b < NBLK2; b += 256) {
        s += (double)partial1[(size_t)b * 512 + c];
        q += (double)partial1[(size_t)b * 512 + 256 + c];
    }
#pragma unroll
    for (int off = 32; off > 0; off >>= 1) {
        s += __shfl_down(s, off);
        q += __shfl_down(q, off);
    }
    if ((t & 63) == 0) { sh[(t >> 6) * 2] = s; sh[(t >> 6) * 2 + 1] = q; }
    __syncthreads();
    if (t == 0) {
        s = sh[0] + sh[2] + sh[4] + sh[6];
        q = sh[1] + sh[3] + sh[5] + sh[7];
        double mean = s / (double)NMR;
        double var  = q / (double)NMR - mean * mean;
        float scale = gamma1[c] * rsqrtf((float)var + BN_EPS);
        bn1[c]       = scale;
        bn1[256 + c] = fmaf(-(float)mean, scale, beta1[c]);
    }
}

// ---------------------------------------------------------------------------
// K3 (pass B) round 6: block = 4 atoms = 48 edge rows, Q-LDS 48x256 bf16 =
// 24 KB (was 48 KB) -> occupancy cap moves LDS(3 blk/CU) -> VGPR(4 blk/CU),
// +33% resident waves for gather-latency hiding. MFMA pads to 2x32-row tiles
// (pad rows clamped + unstored; MFMA is 5% util, waste is free). P1 + bn1
// loads issued at kernel top + nidx staged to LDS -> fly over W-pack + MFMA.
// ONE barrier in the main phase (was 2). Reg budget ~100 unified < 128 cap,
// so (256,4) cannot trigger the round-3 spill trap.
// ---------------------------------------------------------------------------
__global__ __launch_bounds__(256, 4) void k3_fused(const float* __restrict__ nbr,
                                                   const int* __restrict__ nidx,
                                                   const float* __restrict__ W,
                                                   const u16* __restrict__ P12,
                                                   const float* __restrict__ bn1,
                                                   float* __restrict__ nsum,
                                                   float* __restrict__ partial2) {
    __shared__ u16 Q[48 * 256];     // 24 KB bf16 Q-tile
    __shared__ int nid[48];
    const int t  = threadIdx.x;
    const int w  = t >> 6;
    const int L  = t & 63;
    const int lr = L & 31, lk = L >> 5;

    const int gblk = blockIdx.x * 48;           // first edge row
    const int a    = t >> 6;                    // atom slot 0..3 (== wave)
    const int c2   = (t & 63) * 2;              // filter col pair base
    const int n    = blockIdx.x * 4 + a;        // global atom

    // ---- early issue: P1 pair + BN1 params (fly over W-pack + MFMA) ----
    const u32 u1f = *(const u32*)&P12[(size_t)n * 512 + c2];
    const u32 u1c = *(const u32*)&P12[(size_t)n * 512 + 128 + c2];
    const float2 scf = *(const float2*)&bn1[c2];
    const float2 shf = *(const float2*)&bn1[256 + c2];
    const float2 scc = *(const float2*)&bn1[128 + c2];
    const float2 shc = *(const float2*)&bn1[384 + c2];

    // stage nidx for the block's 48 edges
    if (t < 48) nid[t] = nidx[gblk + t];

    // stationary B frags: wave w covers cols w*64 + ct*32 + lr, k in [256,320)
    short8 bfrag[2][4];
#pragma unroll
    for (int ct = 0; ct < 2; ct++) {
        const float* wr = &W[(size_t)(w * 64 + ct * 32 + lr) * KIN + 256];
#pragma unroll
        for (int s = 0; s < 4; s++) {
            float4 x = *(const float4*)&wr[s * 16 + lk * 8];
            float4 y = *(const float4*)&wr[s * 16 + lk * 8 + 4];
            bfrag[ct][s] = pack8(x, y);
        }
    }

    // ---- Q = nbr @ W3^T, two 32-row tiles (rows 48..63 are pad) ----
#pragma unroll
    for (int st = 0; st < 2; st++) {
        int er = gblk + st * 32 + lr;
        if (er > gblk + 47) er = gblk + 47;     // clamp pad rows (in-bounds)
        const float* ar = &nbr[(size_t)er * KD + lk * 8];
        f32x16 acc[2];
#pragma unroll
        for (int p = 0; p < 16; p++) { acc[0][p] = 0.f; acc[1][p] = 0.f; }
#pragma unroll
        for (int s = 0; s < 4; s++) {
            float4 x = *(const float4*)&ar[s * 16];
            float4 y = *(const float4*)&ar[s * 16 + 4];
            short8 af = pack8(x, y);
            acc[0] = __builtin_amdgcn_mfma_f32_32x32x16_bf16(af, bfrag[0][s], acc[0], 0, 0, 0);
            acc[1] = __builtin_amdgcn_mfma_f32_32x32x16_bf16(af, bfrag[1][s], acc[1], 0, 0, 0);
        }
#pragma unroll
        for (int ct = 0; ct < 2; ct++) {
            const int col = w * 64 + ct * 32 + lr;
#pragma unroll
            for (int p = 0; p < 16; p++) {
                if (st == 0 || p < 8) {         // row < 48 only
                    const int row = st * 32 + (p & 3) + 8 * (p >> 2) + 4 * lk;
                    Q[row * 256 + col] = (u16)(f2bf_bits(acc[ct][p]) >> 16);
                }
            }
        }
    }
    __syncthreads();

    // ---- epilogue: thread = (atom a, 2 filter cols + 2 core cols) ----
    const float p1f0 = bflo(u1f), p1f1 = bfhi(u1f);
    const float p1c0 = bflo(u1c), p1c1 = bfhi(u1c);
    float s2[2] = {0.f, 0.f};
#pragma unroll
    for (int m = 0; m < 12; m++) {
        const int iv   = nid[a * 12 + m];
        const float mk = (iv != 0) ? 1.f : 0.f;
        const int row  = a * 12 + m;
        const u32 qf  = *(const u32*)&Q[row * 256 + c2];
        const u32 qc  = *(const u32*)&Q[row * 256 + 128 + c2];
        const u32 u2f = *(const u32*)&P12[(size_t)iv * 512 + 256 + c2];
        const u32 u2c = *(const u32*)&P12[(size_t)iv * 512 + 384 + c2];

        float vf0 = p1f0 + mk * (bflo(u2f) + bflo(qf));
        float vf1 = p1f1 + mk * (bfhi(u2f) + bfhi(qf));
        float vc0 = p1c0 + mk * (bflo(u2c) + bflo(qc));
        float vc1 = p1c1 + mk * (bfhi(u2c) + bfhi(qc));

        float xf0 = fmaf(vf0, scf.x, shf.x), xc0 = fmaf(vc0, scc.x, shc.x);
        float xf1 = fmaf(vf1, scf.y, shf.y), xc1 = fmaf(vc1, scc.y, shc.y);

        s2[0] += fast_sigmoid(xf0) * fast_softplus(xc0) * mk;
        s2[1] += fast_sigmoid(xf1) * fast_softplus(xc1) * mk;
    }

    *(float2*)&nsum[(size_t)n * 128 + c2] = make_float2(s2[0], s2[1]);

    // ---- BN2 partials: reuse Q LDS as float scratch (4 KB) ----
    __syncthreads();
    float* red = (float*)Q;
    *(float2*)&red[a * 128 + c2]       = make_float2(s2[0], s2[1]);
    *(float2*)&red[512 + a * 128 + c2] = make_float2(s2[0] * s2[0], s2[1] * s2[1]);
    __syncthreads();
    if (t < 128) {
        float s = 0.f, q = 0.f;
#pragma unroll
        for (int a2 = 0; a2 < 4; a2++) {
            s += red[a2 * 128 + t];
            q += red[512 + a2 * 128 + t];
        }
        partial2[(size_t)blockIdx.x * 256 + t]       = s;
        partial2[(size_t)blockIdx.x * 256 + 128 + t] = q;
    }
}

// ---------------------------------------------------------------------------
// K3b: finalize BN2 (unchanged; NBLKB now 12500 -> ~49 iters/thread)
// ---------------------------------------------------------------------------
__global__ __launch_bounds__(256) void k3b_bn2(const float* __restrict__ partial2,
                                               const float* __restrict__ gamma2,
                                               const float* __restrict__ beta2,
                                               float* __restrict__ bn2) {
    __shared__ double sh[8];
    const int c = blockIdx.x;
    const int t = threadIdx.x;
    double s = 0.0, q = 0.0;
    for (int b = t; b < NBLKB; b += 256) {
        s += (double)partial2[(size_t)b * 256 + c];
        q += (double)partial2[(size_t)b * 256 + 128 + c];
    }
#pragma unroll
    for (int off = 32; off > 0; off >>= 1) {
        s += __shfl_down(s, off);
        q += __shfl_down(q, off);
    }
    if ((t & 63) == 0) { sh[(t >> 6) * 2] = s; sh[(t >> 6) * 2 + 1] = q; }
    __syncthreads();
    if (t == 0) {
        s = sh[0] + sh[2] + sh[4] + sh[6];
        q = sh[1] + sh[3] + sh[5] + sh[7];
        double mean = s / (double)NA;
        double var  = q / (double)NA - mean * mean;
        float scale = gamma2[c] * rsqrtf((float)var + BN_EPS);
        bn2[c]       = scale;
        bn2[128 + c] = fmaf(-(float)mean, scale, beta2[c]);
    }
}

// ---------------------------------------------------------------------------
// K4: out = softplus(atom_in + nbr_sumed*scale2 + shift2)
// ---------------------------------------------------------------------------
__global__ __launch_bounds__(256) void k4_out(const float* __restrict__ atom,
                                              const float* __restrict__ nsum,
                                              const float* __restrict__ bn2,
                                              float* __restrict__ out) {
    const int i  = blockIdx.x * 256 + threadIdx.x;   // float4 index, 1.6M exact
    const int c0 = (i & 31) * 4;
    float4 a = ((const float4*)atom)[i];
    float4 s = ((const float4*)nsum)[i];
    float4 r;
    r.x = fast_softplus(a.x + fmaf(s.x, bn2[c0 + 0], bn2[128 + c0 + 0]));
    r.y = fast_softplus(a.y + fmaf(s.y, bn2[c0 + 1], bn2[128 + c0 + 1]));
    r.z = fast_softplus(a.z + fmaf(s.z, bn2[c0 + 2], bn2[128 + c0 + 2]));
    r.w = fast_softplus(a.w + fmaf(s.w, bn2[c0 + 3], bn2[128 + c0 + 3]));
    ((float4*)out)[i] = r;
}

// ---------------------------------------------------------------------------
extern "C" void kernel_launch(void* const* d_in, const int* in_sizes, int n_in,
                              void* d_out, int out_size, void* d_ws, size_t ws_size,
                              hipStream_t stream) {
    const float* atom   = (const float*)d_in[0];
    const float* nbr    = (const float*)d_in[1];
    const int*   nidx   = (const int*)d_in[2];
    const float* W      = (const float*)d_in[3];
    // d_in[4] = b : unused — cancels exactly through BN1 mean subtraction
    const float* gamma1 = (const float*)d_in[5];
    const float* beta1  = (const float*)d_in[6];
    const float* gamma2 = (const float*)d_in[7];
    const float* beta2  = (const float*)d_in[8];
    float* out = (float*)d_out;

    // ws layout: P12 bf16 (51.2MB) | nsum (25.6MB) | partial1 | partial2 | bn
    u16* P12        = (u16*)d_ws;
    float* nsum     = (float*)(P12 + (size_t)NA * 512);
    float* partial1 = nsum + (size_t)NA * 128;
    float* partial2 = partial1 + (size_t)NBLK2 * 512;
    float* bn1      = partial2 + (size_t)NBLKB * 256;
    float* bn2      = bn1 + 512;

    k1_p12  <<<dim3(256, 2), 256, 0, stream>>>(atom, W, P12);
    k2_stats<<<NBLK2,        256, 0, stream>>>(nbr, nidx, W, P12, partial1);
    k2b_bn1 <<<256,          256, 0, stream>>>(partial1, gamma1, beta1, bn1);
    k3_fused<<<NBLKB,        256, 0, stream>>>(nbr, nidx, W, P12, bn1, nsum, partial2);
    k3b_bn2 <<<128,          256, 0, stream>>>(partial2, gamma2, beta2, bn2);
    k4_out  <<<6250,         256, 0, stream>>>(atom, nsum, bn2, out);
}

// Round 8
// 545.217 us; speedup vs baseline: 1.0834x; 1.0834x over previous
//
#include <hip/hip_runtime.h>

typedef unsigned int u32;
typedef unsigned short u16;
typedef __attribute__((ext_vector_type(8))) short short8;
typedef __attribute__((ext_vector_type(16))) float f32x16;

// Problem constants
#define NA   50000      // atoms
#define MN   12         // neighbors
#define FD   128        // atom feature len
#define KD   64         // nbr feature len
#define NMR  600000     // NA*MN edge rows
#define KIN  320        // 2F+K
#define NT2  9375       // NMR/64 tiles (pass A)
#define NBLK2 1024      // pass-A persistent blocks
#define NBLKB 6250      // pass-B blocks: 8 atoms = 96 edge rows each
#define NCH1 1563       // k1 row-chunks of 32 (ceil(50000/32))
#define BN_EPS 1e-5f
#define LOG2E 1.4426950408889634f
#define LN2   0.6931471805599453f

// ---- fast transcendentals: raw v_exp_f32 / v_log_f32 / v_rcp_f32 ----
#if __has_builtin(__builtin_amdgcn_exp2f)
#define EXP2F(x) __builtin_amdgcn_exp2f(x)
#else
#define EXP2F(x) exp2f(x)
#endif
#if __has_builtin(__builtin_amdgcn_logf)
#define LOG2F(x) __builtin_amdgcn_logf(x)
#else
#define LOG2F(x) log2f(x)
#endif
#if __has_builtin(__builtin_amdgcn_rcpf)
#define RCPF(x) __builtin_amdgcn_rcpf(x)
#else
#define RCPF(x) (1.f / (x))
#endif

__device__ __forceinline__ float fast_sigmoid(float x) {
    return RCPF(1.f + EXP2F(-x * LOG2E));    // 1/(1+e^-x)
}
__device__ __forceinline__ float fast_softplus(float x) {
    float e = EXP2F(-fabsf(x) * LOG2E);      // e^{-|x|}
    return fmaxf(x, 0.f) + LN2 * LOG2F(1.f + e);
}

// ---- manual bf16 (RNE) helpers ----
__device__ __forceinline__ u32 f2bf_bits(float f) {
    u32 u = __float_as_uint(f);
    return u + 0x7fffu + ((u >> 16) & 1u);
}
__device__ __forceinline__ u32 pack2(float lo, float hi) {
    return (f2bf_bits(lo) >> 16) | (f2bf_bits(hi) & 0xffff0000u);
}
__device__ __forceinline__ float bflo(u32 u) { return __uint_as_float(u << 16); }
__device__ __forceinline__ float bfhi(u32 u) { return __uint_as_float(u & 0xffff0000u); }
__device__ __forceinline__ short8 pack8(float4 x, float4 y) {
    union { short8 s; uint4 u; } cv;
    cv.u = make_uint4(pack2(x.x, x.y), pack2(x.z, x.w),
                      pack2(y.x, y.y), pack2(y.z, y.w));
    return cv.s;
}

// ---------------------------------------------------------------------------
// K1 (MFMA, persistent): UNCHANGED from round 5 (control).
// ---------------------------------------------------------------------------
__global__ __launch_bounds__(256) void k1_p12(const float* __restrict__ atom,
                                              const float* __restrict__ W,
                                              u16* __restrict__ P12) {
    __shared__ u16 C16[32 * 256];   // 16 KB: one 32-row x 256-col bf16 chunk
    const int t  = threadIdx.x;
    const int w  = t >> 6;
    const int L  = t & 63;
    const int lr = L & 31, lk = L >> 5;
    const int yb = blockIdx.y;      // 0: P1 (k 0..127), 1: P2 (k 128..255)
    const int kw = yb * 128;

    short8 bfrag[2][8];
#pragma unroll
    for (int ct = 0; ct < 2; ct++) {
        const float* wr = &W[(size_t)(w * 64 + ct * 32 + lr) * KIN + kw];
#pragma unroll
        for (int s = 0; s < 8; s++) {
            float4 x = *(const float4*)&wr[s * 16 + lk * 8];
            float4 y = *(const float4*)&wr[s * 16 + lk * 8 + 4];
            bfrag[ct][s] = pack8(x, y);
        }
    }

    int ci = blockIdx.x;
    float4 ax[8], ay[8];
    {
        int row = ci * 32 + lr; if (row > NA - 1) row = NA - 1;
        const float* ar = &atom[(size_t)row * FD];
#pragma unroll
        for (int s = 0; s < 8; s++) {
            ax[s] = *(const float4*)&ar[s * 16 + lk * 8];
            ay[s] = *(const float4*)&ar[s * 16 + lk * 8 + 4];
        }
    }

    for (; ci < NCH1; ci += 256) {
        short8 af[8];
#pragma unroll
        for (int s = 0; s < 8; s++) af[s] = pack8(ax[s], ay[s]);

        const int next = ci + 256;
        if (next < NCH1) {
            int row = next * 32 + lr; if (row > NA - 1) row = NA - 1;
            const float* ar = &atom[(size_t)row * FD];
#pragma unroll
            for (int s = 0; s < 8; s++) {
                ax[s] = *(const float4*)&ar[s * 16 + lk * 8];
                ay[s] = *(const float4*)&ar[s * 16 + lk * 8 + 4];
            }
        }

        f32x16 acc[2];
#pragma unroll
        for (int p = 0; p < 16; p++) { acc[0][p] = 0.f; acc[1][p] = 0.f; }
#pragma unroll
        for (int s = 0; s < 8; s++) {
            acc[0] = __builtin_amdgcn_mfma_f32_32x32x16_bf16(af[s], bfrag[0][s], acc[0], 0, 0, 0);
            acc[1] = __builtin_amdgcn_mfma_f32_32x32x16_bf16(af[s], bfrag[1][s], acc[1], 0, 0, 0);
        }

        __syncthreads();
#pragma unroll
        for (int ct = 0; ct < 2; ct++) {
            const int col = w * 64 + ct * 32 + lr;
#pragma unroll
            for (int p = 0; p < 16; p++) {
                const int r = (p & 3) + 8 * (p >> 2) + 4 * lk;
                C16[r * 256 + col] = (u16)(f2bf_bits(acc[ct][p]) >> 16);
            }
        }
        __syncthreads();

        const int r0 = ci * 32;
#pragma unroll
        for (int i = 0; i < 4; i++) {
            const int flat = t + i * 256;
            const int row  = flat >> 5;
            const int seg  = flat & 31;
            if (r0 + row < NA)
                *(uint4*)&P12[(size_t)(r0 + row) * 512 + yb * 256 + seg * 8] =
                    *(const uint4*)&C16[row * 256 + seg * 8];
        }
    }
}

// ---------------------------------------------------------------------------
// K2 (pass A, BN1 stats): UNCHANGED from round 5 (control).
// ---------------------------------------------------------------------------
__global__ __launch_bounds__(256, 2) void k2_stats(const float* __restrict__ nbr,
                                                   const int* __restrict__ nidx,
                                                   const float* __restrict__ W,
                                                   const u16* __restrict__ P12,
                                                   float* __restrict__ partial1) {
    __shared__ u16 C16[64 * 256];     // 32 KB bf16 staging
    const int t  = threadIdx.x;
    const int w  = t >> 6;
    const int L  = t & 63;
    const int rg = w & 1;
    const int cg = w >> 1;
    const int lr = L & 31;
    const int lk = L >> 5;

    short8 bfrag[4][4];
#pragma unroll
    for (int ct = 0; ct < 4; ct++) {
        const float* wr = &W[(size_t)(cg * 128 + ct * 32 + lr) * KIN + 256];
#pragma unroll
        for (int s = 0; s < 4; s++) {
            float4 x = *(const float4*)&wr[s * 16 + lk * 8];
            float4 y = *(const float4*)&wr[s * 16 + lk * 8 + 4];
            bfrag[ct][s] = pack8(x, y);
        }
    }

    const int c0 = (t & 63) * 4;
    float ssum[4] = {0.f, 0.f, 0.f, 0.f};
    float ssq[4]  = {0.f, 0.f, 0.f, 0.f};

    int tile = blockIdx.x;
    float4 a0[4], a1[4];
    {
        const float* ar = &nbr[(size_t)(tile * 64 + rg * 32 + lr) * KD];
#pragma unroll
        for (int s = 0; s < 4; s++) {
            a0[s] = *(const float4*)&ar[s * 16 + lk * 8];
            a1[s] = *(const float4*)&ar[s * 16 + lk * 8 + 4];
        }
    }

    for (; tile < NT2; tile += NBLK2) {
        short8 af[4];
#pragma unroll
        for (int s = 0; s < 4; s++) af[s] = pack8(a0[s], a1[s]);

        const int next = tile + NBLK2;
        if (next < NT2) {
            const float* ar = &nbr[(size_t)(next * 64 + rg * 32 + lr) * KD];
#pragma unroll
            for (int s = 0; s < 4; s++) {
                a0[s] = *(const float4*)&ar[s * 16 + lk * 8];
                a1[s] = *(const float4*)&ar[s * 16 + lk * 8 + 4];
            }
        }

        f32x16 acc[4];
#pragma unroll
        for (int ct = 0; ct < 4; ct++)
#pragma unroll
            for (int p = 0; p < 16; p++) acc[ct][p] = 0.f;
#pragma unroll
        for (int s = 0; s < 4; s++)
#pragma unroll
            for (int ct = 0; ct < 4; ct++)
                acc[ct] = __builtin_amdgcn_mfma_f32_32x32x16_bf16(
                              af[s], bfrag[ct][s], acc[ct], 0, 0, 0);

        __syncthreads();
#pragma unroll
        for (int ct = 0; ct < 4; ct++) {
            const int col = cg * 128 + ct * 32 + lr;
#pragma unroll
            for (int p = 0; p < 16; p++) {
                int r = rg * 32 + (p & 3) + 8 * (p >> 2) + 4 * lk;
                C16[r * 256 + col] = (u16)(f2bf_bits(acc[ct][p]) >> 16);
            }
        }
        __syncthreads();

#pragma unroll 8
        for (int rr = 0; rr < 16; rr++) {
            const int lrow = rr * 4 + w;
            const int g    = tile * 64 + lrow;
            const u32 n    = (u32)g / 12u;
            const int iv   = nidx[g];
            const float mk = (iv != 0) ? 1.f : 0.f;
            uint2 qv = *(const uint2*)&C16[lrow * 256 + c0];
            uint2 u1 = *(const uint2*)&P12[(size_t)n * 512 + c0];
            uint2 u2 = *(const uint2*)&P12[(size_t)iv * 512 + 256 + c0];
            float v0 = bflo(u1.x) + mk * (bflo(u2.x) + bflo(qv.x));
            float v1 = bfhi(u1.x) + mk * (bfhi(u2.x) + bfhi(qv.x));
            float v2 = bflo(u1.y) + mk * (bflo(u2.y) + bflo(qv.y));
            float v3 = bfhi(u1.y) + mk * (bfhi(u2.y) + bfhi(qv.y));
            ssum[0] += v0; ssq[0] = fmaf(v0, v0, ssq[0]);
            ssum[1] += v1; ssq[1] = fmaf(v1, v1, ssq[1]);
            ssum[2] += v2; ssq[2] = fmaf(v2, v2, ssq[2]);
            ssum[3] += v3; ssq[3] = fmaf(v3, v3, ssq[3]);
        }
    }

    __syncthreads();
    float* red = (float*)C16;
#pragma unroll
    for (int qq = 0; qq < 4; qq++) red[w * 256 + c0 + qq] = ssum[qq];
    __syncthreads();
    {
        float s = red[t] + red[256 + t] + red[512 + t] + red[768 + t];
        partial1[(size_t)blockIdx.x * 512 + t] = s;
    }
    __syncthreads();
#pragma unroll
    for (int qq = 0; qq < 4; qq++) red[w * 256 + c0 + qq] = ssq[qq];
    __syncthreads();
    {
        float s = red[t] + red[256 + t] + red[512 + t] + red[768 + t];
        partial1[(size_t)blockIdx.x * 512 + 256 + t] = s;
    }
}

// ---------------------------------------------------------------------------
// K2b: finalize BN1 (unchanged)
// ---------------------------------------------------------------------------
__global__ __launch_bounds__(256) void k2b_bn1(const float* __restrict__ partial1,
                                               const float* __restrict__ gamma1,
                                               const float* __restrict__ beta1,
                                               float* __restrict__ bn1) {
    __shared__ double sh[8];
    const int c = blockIdx.x;
    const int t = threadIdx.x;
    double s = 0.0, q = 0.0;
    for (int b = t; b < NBLK2; b += 256) {
        s += (double)partial1[(size_t)b * 512 + c];
        q += (double)partial1[(size_t)b * 512 + 256 + c];
    }
#pragma unroll
    for (int off = 32; off > 0; off >>= 1) {
        s += __shfl_down(s, off);
        q += __shfl_down(q, off);
    }
    if ((t & 63) == 0) { sh[(t >> 6) * 2] = s; sh[(t >> 6) * 2 + 1] = q; }
    __syncthreads();
    if (t == 0) {
        s = sh[0] + sh[2] + sh[4] + sh[6];
        q = sh[1] + sh[3] + sh[5] + sh[7];
        double mean = s / (double)NMR;
        double var  = q / (double)NMR - mean * mean;
        float scale = gamma1[c] * rsqrtf((float)var + BN_EPS);
        bn1[c]       = scale;
        bn1[256 + c] = fmaf(-(float)mean, scale, beta1[c]);
    }
}

// ---------------------------------------------------------------------------
// K3 (pass B) round 8: round-5 structure (8 atoms, 96 rows, 48 KB Q-LDS,
// thread = (atom t>>5, 4 cols)) + BATCHED GATHER PREFETCH: all 12 nidx
// loaded as 3x int4, then ALL 24 uint2 P12 gathers issued into register
// arrays BEFORE the W-pack/MFMA phase -- ~500-900cy gather latency hides
// under the entire MFMA phase, and the compute loop runs load-free.
// Round-7 lesson: MLP-per-thread, not occupancy, is the lever.
// launch_bounds(256,3): cap 170 >= est ~145 regs, LDS binds at 3 blk/CU.
// ---------------------------------------------------------------------------
__global__ __launch_bounds__(256, 3) void k3_fused(const float* __restrict__ nbr,
                                                   const int* __restrict__ nidx,
                                                   const float* __restrict__ W,
                                                   const u16* __restrict__ P12,
                                                   const float* __restrict__ bn1,
                                                   float* __restrict__ nsum,
                                                   float* __restrict__ partial2) {
    __shared__ u16 Q[96 * 256];   // 48 KB bf16 Q-tile
    const int t  = threadIdx.x;
    const int w  = t >> 6;
    const int L  = t & 63;
    const int lr = L & 31, lk = L >> 5;

    // epilogue identity: thread = (atom a, filter cols c0..c0+3, core +128)
    const int a  = t >> 5;            // 0..7
    const int c0 = (t & 31) * 4;
    const int n  = blockIdx.x * 8 + a;

    // ---- batch nidx: 12 contiguous ints, 48B, 16B-aligned ----
    const int4 nv0 = *(const int4*)&nidx[(size_t)n * 12];
    const int4 nv1 = *(const int4*)&nidx[(size_t)n * 12 + 4];
    const int4 nv2 = *(const int4*)&nidx[(size_t)n * 12 + 8];
    int iv[12];
    iv[0] = nv0.x; iv[1] = nv0.y; iv[2]  = nv0.z; iv[3]  = nv0.w;
    iv[4] = nv1.x; iv[5] = nv1.y; iv[6]  = nv1.z; iv[7]  = nv1.w;
    iv[8] = nv2.x; iv[9] = nv2.y; iv[10] = nv2.z; iv[11] = nv2.w;

    // ---- issue ALL 24 gathers now; latency hides under W-pack + MFMA ----
    uint2 g2f[12], g2c[12];
#pragma unroll
    for (int m = 0; m < 12; m++) {
        g2f[m] = *(const uint2*)&P12[(size_t)iv[m] * 512 + 256 + c0];
        g2c[m] = *(const uint2*)&P12[(size_t)iv[m] * 512 + 384 + c0];
    }

    // ---- P1 + BN1 params (also early) ----
    const uint2 u1f = *(const uint2*)&P12[(size_t)n * 512 + c0];
    const uint2 u1c = *(const uint2*)&P12[(size_t)n * 512 + 128 + c0];
    const float4 scf = *(const float4*)&bn1[c0];
    const float4 shf = *(const float4*)&bn1[256 + c0];
    const float4 scc = *(const float4*)&bn1[128 + c0];
    const float4 shc = *(const float4*)&bn1[384 + c0];

    // ---- stationary B frags: cols w*64 + ct*32 + lr, k in [256,320) ----
    short8 bfrag[2][4];
#pragma unroll
    for (int ct = 0; ct < 2; ct++) {
        const float* wr = &W[(size_t)(w * 64 + ct * 32 + lr) * KIN + 256];
#pragma unroll
        for (int s = 0; s < 4; s++) {
            float4 x = *(const float4*)&wr[s * 16 + lk * 8];
            float4 y = *(const float4*)&wr[s * 16 + lk * 8 + 4];
            bfrag[ct][s] = pack8(x, y);
        }
    }

    // ---- Q = nbr @ W3^T, three 32-row tiles -> bf16 LDS ----
    const int rbase = blockIdx.x * 96;
#pragma unroll 1
    for (int st = 0; st < 3; st++) {
        const float* ar = &nbr[(size_t)(rbase + st * 32 + lr) * KD + lk * 8];
        f32x16 acc[2];
#pragma unroll
        for (int p = 0; p < 16; p++) { acc[0][p] = 0.f; acc[1][p] = 0.f; }
#pragma unroll
        for (int s = 0; s < 4; s++) {
            float4 x = *(const float4*)&ar[s * 16];
            float4 y = *(const float4*)&ar[s * 16 + 4];
            short8 af = pack8(x, y);
            acc[0] = __builtin_amdgcn_mfma_f32_32x32x16_bf16(af, bfrag[0][s], acc[0], 0, 0, 0);
            acc[1] = __builtin_amdgcn_mfma_f32_32x32x16_bf16(af, bfrag[1][s], acc[1], 0, 0, 0);
        }
#pragma unroll
        for (int ct = 0; ct < 2; ct++) {
            const int col = w * 64 + ct * 32 + lr;
#pragma unroll
            for (int p = 0; p < 16; p++) {
                const int row = st * 32 + (p & 3) + 8 * (p >> 2) + 4 * lk;
                Q[row * 256 + col] = (u16)(f2bf_bits(acc[ct][p]) >> 16);
            }
        }
    }
    __syncthreads();

    // ---- load-free compute loop: staged gathers + Q from LDS ----
    const float p1f0 = bflo(u1f.x), p1f1 = bfhi(u1f.x), p1f2 = bflo(u1f.y), p1f3 = bfhi(u1f.y);
    const float p1c0 = bflo(u1c.x), p1c1 = bfhi(u1c.x), p1c2 = bflo(u1c.y), p1c3 = bfhi(u1c.y);

    float s4[4] = {0.f, 0.f, 0.f, 0.f};
#pragma unroll
    for (int m = 0; m < 12; m++) {
        const float mk = (iv[m] != 0) ? 1.f : 0.f;
        const int row = a * 12 + m;
        const uint2 qf = *(const uint2*)&Q[row * 256 + c0];
        const uint2 qc = *(const uint2*)&Q[row * 256 + 128 + c0];
        const uint2 u2f = g2f[m];
        const uint2 u2c = g2c[m];

        float vf0 = p1f0 + mk * (bflo(u2f.x) + bflo(qf.x));
        float vf1 = p1f1 + mk * (bfhi(u2f.x) + bfhi(qf.x));
        float vf2 = p1f2 + mk * (bflo(u2f.y) + bflo(qf.y));
        float vf3 = p1f3 + mk * (bfhi(u2f.y) + bfhi(qf.y));
        float vc0 = p1c0 + mk * (bflo(u2c.x) + bflo(qc.x));
        float vc1 = p1c1 + mk * (bfhi(u2c.x) + bfhi(qc.x));
        float vc2 = p1c2 + mk * (bflo(u2c.y) + bflo(qc.y));
        float vc3 = p1c3 + mk * (bfhi(u2c.y) + bfhi(qc.y));

        float xf0 = fmaf(vf0, scf.x, shf.x), xc0 = fmaf(vc0, scc.x, shc.x);
        float xf1 = fmaf(vf1, scf.y, shf.y), xc1 = fmaf(vc1, scc.y, shc.y);
        float xf2 = fmaf(vf2, scf.z, shf.z), xc2 = fmaf(vc2, scc.z, shc.z);
        float xf3 = fmaf(vf3, scf.w, shf.w), xc3 = fmaf(vc3, scc.w, shc.w);

        s4[0] += fast_sigmoid(xf0) * fast_softplus(xc0) * mk;
        s4[1] += fast_sigmoid(xf1) * fast_softplus(xc1) * mk;
        s4[2] += fast_sigmoid(xf2) * fast_softplus(xc2) * mk;
        s4[3] += fast_sigmoid(xf3) * fast_softplus(xc3) * mk;
    }

    *(float4*)&nsum[(size_t)n * 128 + c0] = make_float4(s4[0], s4[1], s4[2], s4[3]);

    // ---- BN2 partials: reuse Q LDS as float scratch (8 KB) ----
    __syncthreads();
    float* red = (float*)Q;
#pragma unroll
    for (int j = 0; j < 4; j++) {
        red[a * 128 + c0 + j]        = s4[j];
        red[1024 + a * 128 + c0 + j] = s4[j] * s4[j];
    }
    __syncthreads();
    if (t < 128) {
        float s = 0.f, q = 0.f;
#pragma unroll
        for (int a2 = 0; a2 < 8; a2++) {
            s += red[a2 * 128 + t];
            q += red[1024 + a2 * 128 + t];
        }
        partial2[(size_t)blockIdx.x * 256 + t]       = s;
        partial2[(size_t)blockIdx.x * 256 + 128 + t] = q;
    }
}

// ---------------------------------------------------------------------------
// K3b: finalize BN2 (256 threads)
// ---------------------------------------------------------------------------
__global__ __launch_bounds__(256) void k3b_bn2(const float* __restrict__ partial2,
                                               const float* __restrict__ gamma2,
                                               const float* __restrict__ beta2,
                                               float* __restrict__ bn2) {
    __shared__ double sh[8];
    const int c = blockIdx.x;
    const int t = threadIdx.x;
    double s = 0.0, q = 0.0;
    for (int b = t; b < NBLKB; b += 256) {
        s += (double)partial2[(size_t)b * 256 + c];
        q += (double)partial2[(size_t)b * 256 + 128 + c];
    }
#pragma unroll
    for (int off = 32; off > 0; off >>= 1) {
        s += __shfl_down(s, off);
        q += __shfl_down(q, off);
    }
    if ((t & 63) == 0) { sh[(t >> 6) * 2] = s; sh[(t >> 6) * 2 + 1] = q; }
    __syncthreads();
    if (t == 0) {
        s = sh[0] + sh[2] + sh[4] + sh[6];
        q = sh[1] + sh[3] + sh[5] + sh[7];
        double mean = s / (double)NA;
        double var  = q / (double)NA - mean * mean;
        float scale = gamma2[c] * rsqrtf((float)var + BN_EPS);
        bn2[c]       = scale;
        bn2[128 + c] = fmaf(-(float)mean, scale, beta2[c]);
    }
}

// ---------------------------------------------------------------------------
// K4: out = softplus(atom_in + nbr_sumed*scale2 + shift2)
// ---------------------------------------------------------------------------
__global__ __launch_bounds__(256) void k4_out(const float* __restrict__ atom,
                                              const float* __restrict__ nsum,
                                              const float* __restrict__ bn2,
                                              float* __restrict__ out) {
    const int i  = blockIdx.x * 256 + threadIdx.x;   // float4 index, 1.6M exact
    const int c0 = (i & 31) * 4;
    float4 a = ((const float4*)atom)[i];
    float4 s = ((const float4*)nsum)[i];
    float4 r;
    r.x = fast_softplus(a.x + fmaf(s.x, bn2[c0 + 0], bn2[128 + c0 + 0]));
    r.y = fast_softplus(a.y + fmaf(s.y, bn2[c0 + 1], bn2[128 + c0 + 1]));
    r.z = fast_softplus(a.z + fmaf(s.z, bn2[c0 + 2], bn2[128 + c0 + 2]));
    r.w = fast_softplus(a.w + fmaf(s.w, bn2[c0 + 3], bn2[128 + c0 + 3]));
    ((float4*)out)[i] = r;
}

// ---------------------------------------------------------------------------
extern "C" void kernel_launch(void* const* d_in, const int* in_sizes, int n_in,
                              void* d_out, int out_size, void* d_ws, size_t ws_size,
                              hipStream_t stream) {
    const float* atom   = (const float*)d_in[0];
    const float* nbr    = (const float*)d_in[1];
    const int*   nidx   = (const int*)d_in[2];
    const float* W      = (const float*)d_in[3];
    // d_in[4] = b : unused — cancels exactly through BN1 mean subtraction
    const float* gamma1 = (const float*)d_in[5];
    const float* beta1  = (const float*)d_in[6];
    const float* gamma2 = (const float*)d_in[7];
    const float* beta2  = (const float*)d_in[8];
    float* out = (float*)d_out;

    // ws layout: P12 bf16 (51.2MB) | nsum (25.6MB) | partial1 | partial2 | bn
    u16* P12        = (u16*)d_ws;
    float* nsum     = (float*)(P12 + (size_t)NA * 512);
    float* partial1 = nsum + (size_t)NA * 128;
    float* partial2 = partial1 + (size_t)NBLK2 * 512;
    float* bn1      = partial2 + (size_t)NBLKB * 256;
    float* bn2      = bn1 + 512;

    k1_p12  <<<dim3(256, 2), 256, 0, stream>>>(atom, W, P12);
    k2_stats<<<NBLK2,        256, 0, stream>>>(nbr, nidx, W, P12, partial1);
    k2b_bn1 <<<256,          256, 0, stream>>>(partial1, gamma1, beta1, bn1);
    k3_fused<<<NBLKB,        256, 0, stream>>>(nbr, nidx, W, P12, bn1, nsum, partial2);
    k3b_bn2 <<<128,          256, 0, stream>>>(partial2, gamma2, beta2, bn2);
    k4_out  <<<6250,         256, 0, stream>>>(atom, nsum, bn2, out);
}

// Round 10
// 505.992 us; speedup vs baseline: 1.1673x; 1.0775x over previous
//
#include <hip/hip_runtime.h>

typedef unsigned int u32;
typedef unsigned short u16;
typedef __attribute__((ext_vector_type(8))) short short8;
typedef __attribute__((ext_vector_type(16))) float f32x16;

// Problem constants
#define NA   50000      // atoms
#define MN   12         // neighbors
#define FD   128        // atom feature len
#define KD   64         // nbr feature len
#define NMR  600000     // NA*MN edge rows
#define KIN  320        // 2F+K
#define NT2  9375       // NMR/64 tiles (pass A)
#define NBLK2 512       // pass-A persistent blocks (round-0 proven ws layout)
#define NBLK3 3125      // k3_stream blocks: 16 atoms = 192 edges each
#define NCH1 1563       // k1 row-chunks of 32 (ceil(50000/32))
#define BN_EPS 1e-5f
#define LOG2E 1.4426950408889634f
#define LN2   0.6931471805599453f

// ---- fast transcendentals: raw v_exp_f32 / v_log_f32 / v_rcp_f32 ----
#if __has_builtin(__builtin_amdgcn_exp2f)
#define EXP2F(x) __builtin_amdgcn_exp2f(x)
#else
#define EXP2F(x) exp2f(x)
#endif
#if __has_builtin(__builtin_amdgcn_logf)
#define LOG2F(x) __builtin_amdgcn_logf(x)
#else
#define LOG2F(x) log2f(x)
#endif
#if __has_builtin(__builtin_amdgcn_rcpf)
#define RCPF(x) __builtin_amdgcn_rcpf(x)
#else
#define RCPF(x) (1.f / (x))
#endif

__device__ __forceinline__ float fast_sigmoid(float x) {
    return RCPF(1.f + EXP2F(-x * LOG2E));    // 1/(1+e^-x)
}
__device__ __forceinline__ float fast_softplus(float x) {
    float e = EXP2F(-fabsf(x) * LOG2E);      // e^{-|x|}
    return fmaxf(x, 0.f) + LN2 * LOG2F(1.f + e);
}

// ---- manual bf16 (RNE) helpers ----
__device__ __forceinline__ u32 f2bf_bits(float f) {
    u32 u = __float_as_uint(f);
    return u + 0x7fffu + ((u >> 16) & 1u);
}
__device__ __forceinline__ u32 pack2(float lo, float hi) {
    return (f2bf_bits(lo) >> 16) | (f2bf_bits(hi) & 0xffff0000u);
}
__device__ __forceinline__ float bflo(u32 u) { return __uint_as_float(u << 16); }
__device__ __forceinline__ float bfhi(u32 u) { return __uint_as_float(u & 0xffff0000u); }
__device__ __forceinline__ short8 pack8(float4 x, float4 y) {
    union { short8 s; uint4 u; } cv;
    cv.u = make_uint4(pack2(x.x, x.y), pack2(x.z, x.w),
                      pack2(y.x, y.y), pack2(y.z, y.w));
    return cv.s;
}
__device__ __forceinline__ void unp8(uint4 u, float* f) {
    f[0] = bflo(u.x); f[1] = bfhi(u.x); f[2] = bflo(u.y); f[3] = bfhi(u.y);
    f[4] = bflo(u.z); f[5] = bfhi(u.z); f[6] = bflo(u.w); f[7] = bfhi(u.w);
}

// ---------------------------------------------------------------------------
// K1 (MFMA, persistent): UNCHANGED from round 5 (proven rounds 5/7/8).
// ---------------------------------------------------------------------------
__global__ __launch_bounds__(256) void k1_p12(const float* __restrict__ atom,
                                              const float* __restrict__ W,
                                              u16* __restrict__ P12) {
    __shared__ u16 C16[32 * 256];   // 16 KB: one 32-row x 256-col bf16 chunk
    const int t  = threadIdx.x;
    const int w  = t >> 6;
    const int L  = t & 63;
    const int lr = L & 31, lk = L >> 5;
    const int yb = blockIdx.y;      // 0: P1 (k 0..127), 1: P2 (k 128..255)
    const int kw = yb * 128;

    short8 bfrag[2][8];
#pragma unroll
    for (int ct = 0; ct < 2; ct++) {
        const float* wr = &W[(size_t)(w * 64 + ct * 32 + lr) * KIN + kw];
#pragma unroll
        for (int s = 0; s < 8; s++) {
            float4 x = *(const float4*)&wr[s * 16 + lk * 8];
            float4 y = *(const float4*)&wr[s * 16 + lk * 8 + 4];
            bfrag[ct][s] = pack8(x, y);
        }
    }

    int ci = blockIdx.x;
    float4 ax[8], ay[8];
    {
        int row = ci * 32 + lr; if (row > NA - 1) row = NA - 1;
        const float* ar = &atom[(size_t)row * FD];
#pragma unroll
        for (int s = 0; s < 8; s++) {
            ax[s] = *(const float4*)&ar[s * 16 + lk * 8];
            ay[s] = *(const float4*)&ar[s * 16 + lk * 8 + 4];
        }
    }

    for (; ci < NCH1; ci += 256) {
        short8 af[8];
#pragma unroll
        for (int s = 0; s < 8; s++) af[s] = pack8(ax[s], ay[s]);

        const int next = ci + 256;
        if (next < NCH1) {
            int row = next * 32 + lr; if (row > NA - 1) row = NA - 1;
            const float* ar = &atom[(size_t)row * FD];
#pragma unroll
            for (int s = 0; s < 8; s++) {
                ax[s] = *(const float4*)&ar[s * 16 + lk * 8];
                ay[s] = *(const float4*)&ar[s * 16 + lk * 8 + 4];
            }
        }

        f32x16 acc[2];
#pragma unroll
        for (int p = 0; p < 16; p++) { acc[0][p] = 0.f; acc[1][p] = 0.f; }
#pragma unroll
        for (int s = 0; s < 8; s++) {
            acc[0] = __builtin_amdgcn_mfma_f32_32x32x16_bf16(af[s], bfrag[0][s], acc[0], 0, 0, 0);
            acc[1] = __builtin_amdgcn_mfma_f32_32x32x16_bf16(af[s], bfrag[1][s], acc[1], 0, 0, 0);
        }

        __syncthreads();
#pragma unroll
        for (int ct = 0; ct < 2; ct++) {
            const int col = w * 64 + ct * 32 + lr;
#pragma unroll
            for (int p = 0; p < 16; p++) {
                const int r = (p & 3) + 8 * (p >> 2) + 4 * lk;
                C16[r * 256 + col] = (u16)(f2bf_bits(acc[ct][p]) >> 16);
            }
        }
        __syncthreads();

        const int r0 = ci * 32;
#pragma unroll
        for (int i = 0; i < 4; i++) {
            const int flat = t + i * 256;
            const int row  = flat >> 5;
            const int seg  = flat & 31;
            if (r0 + row < NA)
                *(uint4*)&P12[(size_t)(r0 + row) * 512 + yb * 256 + seg * 8] =
                    *(const uint4*)&C16[row * 256 + seg * 8];
        }
    }
}

// ---------------------------------------------------------------------------
// K2 (gather pass, ONCE): 512 persistent blocks (round-0 grid => round-0
// byte-identical ws layout), bf16 LDS staging (proven rounds 5-8), gated
// bf16 store (proven round 0). Feeds BN1 stats AND the stream pass.
// ---------------------------------------------------------------------------
__global__ __launch_bounds__(256, 2) void k2_gated(const float* __restrict__ nbr,
                                                   const int* __restrict__ nidx,
                                                   const float* __restrict__ W,
                                                   const u16* __restrict__ P12,
                                                   u16* __restrict__ gated,
                                                   float* __restrict__ partial1) {
    __shared__ u16 C16[64 * 256];     // 32 KB bf16 staging
    const int t  = threadIdx.x;
    const int w  = t >> 6;
    const int L  = t & 63;
    const int rg = w & 1;
    const int cg = w >> 1;
    const int lr = L & 31;
    const int lk = L >> 5;

    short8 bfrag[4][4];
#pragma unroll
    for (int ct = 0; ct < 4; ct++) {
        const float* wr = &W[(size_t)(cg * 128 + ct * 32 + lr) * KIN + 256];
#pragma unroll
        for (int s = 0; s < 4; s++) {
            float4 x = *(const float4*)&wr[s * 16 + lk * 8];
            float4 y = *(const float4*)&wr[s * 16 + lk * 8 + 4];
            bfrag[ct][s] = pack8(x, y);
        }
    }

    const int c0 = (t & 63) * 4;
    float ssum[4] = {0.f, 0.f, 0.f, 0.f};
    float ssq[4]  = {0.f, 0.f, 0.f, 0.f};

    int tile = blockIdx.x;
    float4 a0[4], a1[4];
    {
        const float* ar = &nbr[(size_t)(tile * 64 + rg * 32 + lr) * KD];
#pragma unroll
        for (int s = 0; s < 4; s++) {
            a0[s] = *(const float4*)&ar[s * 16 + lk * 8];
            a1[s] = *(const float4*)&ar[s * 16 + lk * 8 + 4];
        }
    }

    for (; tile < NT2; tile += NBLK2) {
        short8 af[4];
#pragma unroll
        for (int s = 0; s < 4; s++) af[s] = pack8(a0[s], a1[s]);

        const int next = tile + NBLK2;
        if (next < NT2) {
            const float* ar = &nbr[(size_t)(next * 64 + rg * 32 + lr) * KD];
#pragma unroll
            for (int s = 0; s < 4; s++) {
                a0[s] = *(const float4*)&ar[s * 16 + lk * 8];
                a1[s] = *(const float4*)&ar[s * 16 + lk * 8 + 4];
            }
        }

        f32x16 acc[4];
#pragma unroll
        for (int ct = 0; ct < 4; ct++)
#pragma unroll
            for (int p = 0; p < 16; p++) acc[ct][p] = 0.f;
#pragma unroll
        for (int s = 0; s < 4; s++)
#pragma unroll
            for (int ct = 0; ct < 4; ct++)
                acc[ct] = __builtin_amdgcn_mfma_f32_32x32x16_bf16(
                              af[s], bfrag[ct][s], acc[ct], 0, 0, 0);

        __syncthreads();
#pragma unroll
        for (int ct = 0; ct < 4; ct++) {
            const int col = cg * 128 + ct * 32 + lr;
#pragma unroll
            for (int p = 0; p < 16; p++) {
                int r = rg * 32 + (p & 3) + 8 * (p >> 2) + 4 * lk;
                C16[r * 256 + col] = (u16)(f2bf_bits(acc[ct][p]) >> 16);
            }
        }
        __syncthreads();

#pragma unroll 8
        for (int rr = 0; rr < 16; rr++) {
            const int lrow = rr * 4 + w;
            const int g    = tile * 64 + lrow;
            const u32 n    = (u32)g / 12u;
            const int iv   = nidx[g];
            const float mk = (iv != 0) ? 1.f : 0.f;
            uint2 qv = *(const uint2*)&C16[lrow * 256 + c0];
            uint2 u1 = *(const uint2*)&P12[(size_t)n * 512 + c0];
            uint2 u2 = *(const uint2*)&P12[(size_t)iv * 512 + 256 + c0];
            float v0 = bflo(u1.x) + mk * (bflo(u2.x) + bflo(qv.x));
            float v1 = bfhi(u1.x) + mk * (bfhi(u2.x) + bfhi(qv.x));
            float v2 = bflo(u1.y) + mk * (bflo(u2.y) + bflo(qv.y));
            float v3 = bfhi(u1.y) + mk * (bfhi(u2.y) + bfhi(qv.y));
            *(uint2*)&gated[(size_t)g * 256 + c0] =
                make_uint2(pack2(v0, v1), pack2(v2, v3));
            ssum[0] += v0; ssq[0] = fmaf(v0, v0, ssq[0]);
            ssum[1] += v1; ssq[1] = fmaf(v1, v1, ssq[1]);
            ssum[2] += v2; ssq[2] = fmaf(v2, v2, ssq[2]);
            ssum[3] += v3; ssq[3] = fmaf(v3, v3, ssq[3]);
        }
    }

    __syncthreads();
    float* red = (float*)C16;
#pragma unroll
    for (int qq = 0; qq < 4; qq++) red[w * 256 + c0 + qq] = ssum[qq];
    __syncthreads();
    {
        float s = red[t] + red[256 + t] + red[512 + t] + red[768 + t];
        partial1[(size_t)blockIdx.x * 512 + t] = s;
    }
    __syncthreads();
#pragma unroll
    for (int qq = 0; qq < 4; qq++) red[w * 256 + c0 + qq] = ssq[qq];
    __syncthreads();
    {
        float s = red[t] + red[256 + t] + red[512 + t] + red[768 + t];
        partial1[(size_t)blockIdx.x * 512 + 256 + t] = s;
    }
}

// ---------------------------------------------------------------------------
// K2b: finalize BN1 (256 threads; NBLK2 = 512 partials)
// ---------------------------------------------------------------------------
__global__ __launch_bounds__(256) void k2b_bn1(const float* __restrict__ partial1,
                                               const float* __restrict__ gamma1,
                                               const float* __restrict__ beta1,
                                               float* __restrict__ bn1) {
    __shared__ double sh[8];
    const int c = blockIdx.x;
    const int t = threadIdx.x;
    double s = 0.0, q = 0.0;
    for (int b = t; b < NBLK2; b += 256) {
        s += (double)partial1[(size_t)b * 512 + c];
        q += (double)partial1[(size_t)b * 512 + 256 + c];
    }
#pragma unroll
    for (int off = 32; off > 0; off >>= 1) {
        s += __shfl_down(s, off);
        q += __shfl_down(q, off);
    }
    if ((t & 63) == 0) { sh[(t >> 6) * 2] = s; sh[(t >> 6) * 2 + 1] = q; }
    __syncthreads();
    if (t == 0) {
        s = sh[0] + sh[2] + sh[4] + sh[6];
        q = sh[1] + sh[3] + sh[5] + sh[7];
        double mean = s / (double)NMR;
        double var  = q / (double)NMR - mean * mean;
        float scale = gamma1[c] * rsqrtf((float)var + BN_EPS);
        bn1[c]       = scale;
        bn1[256 + c] = fmaf(-(float)mean, scale, beta1[c]);
    }
}

// ---------------------------------------------------------------------------
// K3 (stream pass): UNCHANGED from round 9 (experimental arm of the bisect).
// NO gathers, NO MFMA -- pure stream of gated; nidx staged to LDS; m-loop
// fully unrolled so the 24 uint4 streaming loads pipeline.
// ---------------------------------------------------------------------------
__global__ __launch_bounds__(256) void k3_stream(const u16* __restrict__ gated,
                                                 const int* __restrict__ nidx,
                                                 const float* __restrict__ bn1,
                                                 float* __restrict__ nsum,
                                                 float* __restrict__ partial2) {
    __shared__ float red[16 * 128];
    __shared__ int nid[192];
    const int t    = threadIdx.x;
    const int slot = t >> 4;          // atom slot 0..15
    const int c8   = (t & 15) * 8;    // filter col base
    const int n    = blockIdx.x * 16 + slot;

    if (t < 192) nid[t] = nidx[(size_t)blockIdx.x * 192 + t];

    float scf[8], shf[8], scc[8], shc[8];
#pragma unroll
    for (int j = 0; j < 8; j++) {
        scf[j] = bn1[c8 + j];       shf[j] = bn1[256 + c8 + j];
        scc[j] = bn1[128 + c8 + j]; shc[j] = bn1[384 + c8 + j];
    }
    float s8[8];
#pragma unroll
    for (int j = 0; j < 8; j++) s8[j] = 0.f;
    __syncthreads();

    const size_t gb = (size_t)n * MN;
#pragma unroll
    for (int m = 0; m < MN; m++) {
        const size_t g = gb + m;
        const float mk = (nid[slot * MN + m] != 0) ? 1.f : 0.f;
        uint4 uf = *(const uint4*)&gated[g * 256 + c8];
        uint4 uc = *(const uint4*)&gated[g * 256 + 128 + c8];
        float f[8], c[8];
        unp8(uf, f); unp8(uc, c);
#pragma unroll
        for (int j = 0; j < 8; j++) {
            float xf = fmaf(f[j], scf[j], shf[j]);
            float xc = fmaf(c[j], scc[j], shc[j]);
            s8[j] += fast_sigmoid(xf) * fast_softplus(xc) * mk;
        }
    }
    *(float4*)&nsum[(size_t)n * 128 + c8]     = make_float4(s8[0], s8[1], s8[2], s8[3]);
    *(float4*)&nsum[(size_t)n * 128 + c8 + 4] = make_float4(s8[4], s8[5], s8[6], s8[7]);

#pragma unroll
    for (int j = 0; j < 8; j++) red[slot * 128 + c8 + j] = s8[j];
    __syncthreads();
    if (t < 128) {
        float s = 0.f;
#pragma unroll
        for (int q = 0; q < 16; q++) s += red[q * 128 + t];
        partial2[(size_t)blockIdx.x * 256 + t] = s;
    }
    __syncthreads();
#pragma unroll
    for (int j = 0; j < 8; j++) { float v = s8[j]; red[slot * 128 + c8 + j] = v * v; }
    __syncthreads();
    if (t < 128) {
        float s = 0.f;
#pragma unroll
        for (int q = 0; q < 16; q++) s += red[q * 128 + t];
        partial2[(size_t)blockIdx.x * 256 + 128 + t] = s;
    }
}

// ---------------------------------------------------------------------------
// K3b: finalize BN2 (256 threads; NBLK3 = 3125 partials)
// ---------------------------------------------------------------------------
__global__ __launch_bounds__(256) void k3b_bn2(const float* __restrict__ partial2,
                                               const float* __restrict__ gamma2,
                                               const float* __restrict__ beta2,
                                               float* __restrict__ bn2) {
    __shared__ double sh[8];
    const int c = blockIdx.x;
    const int t = threadIdx.x;
    double s = 0.0, q = 0.0;
    for (int b = t; b < NBLK3; b += 256) {
        s += (double)partial2[(size_t)b * 256 + c];
        q += (double)partial2[(size_t)b * 256 + 128 + c];
    }
#pragma unroll
    for (int off = 32; off > 0; off >>= 1) {
        s += __shfl_down(s, off);
        q += __shfl_down(q, off);
    }
    if ((t & 63) == 0) { sh[(t >> 6) * 2] = s; sh[(t >> 6) * 2 + 1] = q; }
    __syncthreads();
    if (t == 0) {
        s = sh[0] + sh[2] + sh[4] + sh[6];
        q = sh[1] + sh[3] + sh[5] + sh[7];
        double mean = s / (double)NA;
        double var  = q / (double)NA - mean * mean;
        float scale = gamma2[c] * rsqrtf((float)var + BN_EPS);
        bn2[c]       = scale;
        bn2[128 + c] = fmaf(-(float)mean, scale, beta2[c]);
    }
}

// ---------------------------------------------------------------------------
// K4: out = softplus(atom_in + nbr_sumed*scale2 + shift2)
// ---------------------------------------------------------------------------
__global__ __launch_bounds__(256) void k4_out(const float* __restrict__ atom,
                                              const float* __restrict__ nsum,
                                              const float* __restrict__ bn2,
                                              float* __restrict__ out) {
    const int i  = blockIdx.x * 256 + threadIdx.x;   // float4 index, 1.6M exact
    const int c0 = (i & 31) * 4;
    float4 a = ((const float4*)atom)[i];
    float4 s = ((const float4*)nsum)[i];
    float4 r;
    r.x = fast_softplus(a.x + fmaf(s.x, bn2[c0 + 0], bn2[128 + c0 + 0]));
    r.y = fast_softplus(a.y + fmaf(s.y, bn2[c0 + 1], bn2[128 + c0 + 1]));
    r.z = fast_softplus(a.z + fmaf(s.z, bn2[c0 + 2], bn2[128 + c0 + 2]));
    r.w = fast_softplus(a.w + fmaf(s.w, bn2[c0 + 3], bn2[128 + c0 + 3]));
    ((float4*)out)[i] = r;
}

// ---------------------------------------------------------------------------
extern "C" void kernel_launch(void* const* d_in, const int* in_sizes, int n_in,
                              void* d_out, int out_size, void* d_ws, size_t ws_size,
                              hipStream_t stream) {
    const float* atom   = (const float*)d_in[0];
    const float* nbr    = (const float*)d_in[1];
    const int*   nidx   = (const int*)d_in[2];
    const float* W      = (const float*)d_in[3];
    // d_in[4] = b : unused — cancels exactly through BN1 mean subtraction
    const float* gamma1 = (const float*)d_in[5];
    const float* beta1  = (const float*)d_in[6];
    const float* gamma2 = (const float*)d_in[7];
    const float* beta2  = (const float*)d_in[8];
    float* out = (float*)d_out;

    // ws layout: BYTE-IDENTICAL to the proven round-0 baseline (388.25 MB):
    // P12 bf16 (51.2MB) | gated bf16 (307.2MB) | nsum | partial1(512) |
    // partial2(3125) | bn1 | bn2
    u16* P12        = (u16*)d_ws;
    u16* gated      = P12 + (size_t)NA * 512;
    float* nsum     = (float*)(gated + (size_t)NMR * 256);
    float* partial1 = nsum + (size_t)NA * 128;
    float* partial2 = partial1 + (size_t)NBLK2 * 512;
    float* bn1      = partial2 + (size_t)NBLK3 * 256;
    float* bn2      = bn1 + 512;

    k1_p12   <<<dim3(256, 2), 256, 0, stream>>>(atom, W, P12);
    k2_gated <<<NBLK2,        256, 0, stream>>>(nbr, nidx, W, P12, gated, partial1);
    k2b_bn1  <<<256,          256, 0, stream>>>(partial1, gamma1, beta1, bn1);
    k3_stream<<<NBLK3,        256, 0, stream>>>(gated, nidx, bn1, nsum, partial2);
    k3b_bn2  <<<128,          256, 0, stream>>>(partial2, gamma2, beta2, bn2);
    k4_out   <<<6250,         256, 0, stream>>>(atom, nsum, bn2, out);
}